// Round 13
// baseline (231.773 us; speedup 1.0000x reference)
//
#include <hip/hip_runtime.h>
#include <math.h>
#include <stdint.h>

#define CIN 256
#define HH 64
#define WW 64
#define HW 4096
#define CHW (CIN * HW) // 1048576

typedef __attribute__((ext_vector_type(8))) short short8;   // 8 bf16 = 4 VGPR (MFMA A/B frag)
typedef __attribute__((ext_vector_type(4))) float float4v;  // MFMA C/D frag

__device__ inline unsigned short f2bf(float f) {
    union { float f; uint32_t u; } v; v.f = f;
    return (unsigned short)((v.u + 0x7FFFu + ((v.u >> 16) & 1u)) >> 16);
}
__device__ inline float bf2f(unsigned short h) {
    union { uint32_t u; float f; } v; v.u = ((uint32_t)h) << 16;
    return v.f;
}
__device__ inline uint4 ld16(const unsigned short* p) {
    uint4 r; __builtin_memcpy(&r, p, 16); return r;
}

// ================= Kernel 1: offset conv, LDS-staged weights (R22-proven) ========================
__global__ __launch_bounds__(256) void k_offset_conv(
    const float* __restrict__ x, const float* __restrict__ w_off,
    float* __restrict__ off_part)
{
    __shared__ float red[4][64][18];
    __shared__ float wlds[32][18][12];   // [ci][co][9 w + 3 pad] = 27.6 KB

    const int bh = blockIdx.x, cg = blockIdx.y;
    const int b = bh >> 6, h = bh & 63;
    const int t = threadIdx.x;
    const int w = t & 63;
    const int wv = __builtin_amdgcn_readfirstlane(t >> 6);

    // cooperative stage: src (co, ci, k) is contiguous per co (c-consecutive 9-blocks)
    for (int i = t; i < 18 * 288; i += 256) {
        int co = i / 288, rem = i - co * 288;   // rem = ci*9 + k
        int ci = rem / 9, k = rem - ci * 9;
        wlds[ci][co][k] = w_off[(size_t)co * (CIN * 9) + (size_t)cg * 288 + rem];
    }
    __syncthreads();

    float acc[18];
#pragma unroll
    for (int i = 0; i < 18; ++i) acc[i] = 0.f;
    const float* xb = x + (size_t)b * CHW;
#pragma unroll 1
    for (int i = 0; i < 8; ++i) {
        const int ci = wv * 8 + i;
        const int c = cg * 32 + ci;
        const float* xc = xb + (size_t)c * HW;
        float r0 = (h > 0)  ? xc[(h - 1) * WW + w] : 0.f;
        float r1 =            xc[h * WW + w];
        float r2 = (h < 63) ? xc[(h + 1) * WW + w] : 0.f;
        float l0 = __shfl_up(r0, 1), l1 = __shfl_up(r1, 1), l2 = __shfl_up(r2, 1);
        float d0 = __shfl_down(r0, 1), d1 = __shfl_down(r1, 1), d2 = __shfl_down(r2, 1);
        if (w == 0)  { l0 = 0.f; l1 = 0.f; l2 = 0.f; }
        if (w == 63) { d0 = 0.f; d1 = 0.f; d2 = 0.f; }
        const float xv[9] = {l0, r0, d0, l1, r1, d1, l2, r2, d2};
#pragma unroll
        for (int co = 0; co < 18; ++co) {
            const float4 wa = *(const float4*)&wlds[ci][co][0];
            const float4 wb = *(const float4*)&wlds[ci][co][4];
            const float w8 = wlds[ci][co][8];
            acc[co] += wa.x * xv[0] + wa.y * xv[1] + wa.z * xv[2] + wa.w * xv[3]
                     + wb.x * xv[4] + wb.y * xv[5] + wb.z * xv[6] + wb.w * xv[7]
                     + w8 * xv[8];
        }
    }
#pragma unroll
    for (int co = 0; co < 18; ++co) red[wv][w][co] = acc[co];
    __syncthreads();
    if (t < 64) {
#pragma unroll
        for (int co = 0; co < 18; ++co) {
            float s = red[0][t][co] + red[1][t][co] + red[2][t][co] + red[3][t][co];
            off_part[((size_t)(cg * 128 + bh)) * 1152 + co * 64 + t] = s;
        }
    }
}

// ================= Kernel 2: patch-form bilinear params (sums 8 conv partials) — R9-proven =======
__global__ __launch_bounds__(256) void k_params(
    const float* __restrict__ off_part, const float* __restrict__ b_off,
    uint2* __restrict__ pbw, uint32_t* __restrict__ pba)
{
    const int bh = blockIdx.x;
    const int h = bh & 63;
    const int t = threadIdx.x;
    for (int r = 0; r < 3; ++r) {
        int sid = t + 256 * r;
        if (sid < 576) {
            int k = sid >> 6, ww = sid & 63;
            float dy = b_off[2 * k], dx = b_off[2 * k + 1];
#pragma unroll
            for (int g = 0; g < 8; ++g) {
                const float* pp = off_part + (size_t)(g * 128 + bh) * 1152;
                dy += pp[(2 * k) * 64 + ww];
                dx += pp[(2 * k + 1) * 64 + ww];
            }
            float py = (float)(h + k / 3 - 1) + dy;
            float px = (float)(ww + k % 3 - 1) + dx;
            float y0f = floorf(py), x0f = floorf(px);
            float fy = py - y0f, fx = px - x0f;
            int y0 = (int)y0f, x0 = (int)x0f;
            int yb = min(max(y0, 0), 62), xb = min(max(x0, 0), 62);
            float wr[2] = {0.f, 0.f}, wc[2] = {0.f, 0.f};
            if (y0 >= 0 && y0 < HH) wr[y0 - yb] += 1.f - fy;
            if (y0 + 1 >= 0 && y0 + 1 < HH) wr[y0 + 1 - yb] += fy;
            if (x0 >= 0 && x0 < WW) wc[x0 - xb] += 1.f - fx;
            if (x0 + 1 >= 0 && x0 + 1 < WW) wc[x0 + 1 - xb] += fx;
            uint2 pw;
            pw.x = (uint32_t)f2bf(wr[0] * wc[0]) | ((uint32_t)f2bf(wr[0] * wc[1]) << 16);
            pw.y = (uint32_t)f2bf(wr[1] * wc[0]) | ((uint32_t)f2bf(wr[1] * wc[1]) << 16);
            pbw[(size_t)bh * 576 + sid] = pw;
            pba[(size_t)bh * 576 + sid] = (uint32_t)(yb * WW + xb);
        }
    }
}

// ================= Kernel 3: W concat + bf16 cast, TAP-MAJOR frag-native layout (R13) ============
__global__ __launch_bounds__(256) void k_wcat(
    const float* __restrict__ wq, const float* __restrict__ wk, const float* __restrict__ wv_,
    const float* __restrict__ bq, const float* __restrict__ bk, const float* __restrict__ bv,
    unsigned short* __restrict__ wf, float* __restrict__ bcat)
{
    int e = (blockIdx.x * 256 + threadIdx.x) * 4;   // flat co*2304+k, 4 consecutive k
    const float* src;
    if (e < 32 * 2304)      src = wq + e;
    else if (e < 64 * 2304) src = wk + (e - 32 * 2304);
    else                    src = wv_ + (e - 64 * 2304);
    float4 v = *(const float4*)src;
    unsigned short o[4] = {f2bf(v.x), f2bf(v.y), f2bf(v.z), f2bf(v.w)};
    int co = e / 2304;
    int k0 = e - co * 2304;
#pragma unroll
    for (int i = 0; i < 4; ++i) {
        int k = k0 + i;
        int c = (k * 7282) >> 16;      // exact /9 for k < 2304
        int tap = k - c * 9;
        int kdp = tap * 256 + c;
        size_t d = ((size_t)(co >> 4) * 72 + (kdp >> 5)) * 512 + (size_t)(co & 15) * 32 + (kdp & 31);
        wf[d] = o[i];
    }
    if (blockIdx.x == 0 && threadIdx.x < 320) {
        int c = threadIdx.x;
        bcat[c] = c < 32 ? bq[c] : (c < 64 ? bk[c - 32] : bv[c - 64]);
    }
}

// ================= Kernel 3b: x NCHW f32 -> NHWC bf16 (channel-dense gather layout) ==============
__global__ __launch_bounds__(256) void k_xt(
    const float* __restrict__ x, unsigned short* __restrict__ xt)
{
    __shared__ float tl[64][65];
    const int b = blockIdx.y, px0 = blockIdx.x * 64;
    const int t = threadIdx.x;
    const float* xb = x + (size_t)b * CHW;
    unsigned short* xo = xt + (size_t)b * CHW;
    for (int cb = 0; cb < 4; ++cb) {
        __syncthreads();
#pragma unroll
        for (int i = 0; i < 16; ++i) {
            int cr = (t >> 6) * 16 + i;
            tl[cr][t & 63] = xb[(size_t)(cb * 64 + cr) * HW + px0 + (t & 63)];
        }
        __syncthreads();
#pragma unroll
        for (int i = 0; i < 2; ++i) {
            int px = t >> 2;
            int sl = (t & 3) + 4 * i;
            union { uint4 v; unsigned short u[8]; } o;
#pragma unroll
            for (int j = 0; j < 8; ++j) o.u[j] = f2bf(tl[sl * 8 + j][px]);
            *(uint4*)(xo + (size_t)(px0 + px) * 256 + cb * 64 + sl * 8) = o.v;
        }
    }
}

// ================= Kernel 4: FUSED sample + GEMM, channel-dense gathers (R13-proven) =============
__global__ __launch_bounds__(256) void k_dgemm(
    const unsigned short* __restrict__ xt, const uint2* __restrict__ pbw,
    const uint32_t* __restrict__ pba, const unsigned short* __restrict__ wf,
    const float* __restrict__ bcat,
    unsigned short* __restrict__ qb16, unsigned short* __restrict__ kb16,
    unsigned short* __restrict__ vb16)
{
    __shared__ uint2 prw2[144];                    // [px*9 + tap]
    __shared__ uint32_t pra2[144];
    __shared__ unsigned short tile[2][4][16][40];  // dbuf x 4 steps x 16px x 32ch(+pad)

    const int blk = blockIdx.x;
    const int b = blk >> 8;
    const int p0 = (blk & 255) * 16;
    const int bh = b * 64 + (p0 >> 6);
    const int w0 = p0 & 63;

    const int t = threadIdx.x;
    const int lane = t & 63;
    const int l15 = lane & 15, quad = lane >> 4;
    const int wvid = __builtin_amdgcn_readfirstlane(t >> 6);

    if (t < 144) {
        int nl9 = t / 9, tap = t - nl9 * 9;
        int src = bh * 576 + tap * 64 + w0 + nl9;
        prw2[nl9 * 9 + tap] = pbw[src];
        pra2[nl9 * 9 + tap] = pba[src];
    }

    const unsigned short* xtb = xt + (size_t)b * CHW;
    const int px = t >> 4;          // pixel 0..15
    const int cl = (t >> 2) & 3;    // c-block-local (step within macro)
    const int sl = t & 3;           // 8-channel slice within 32

    float4v acc[5];
#pragma unroll
    for (int s = 0; s < 5; ++s) acc[s] = (float4v){0.f, 0.f, 0.f, 0.f};

    const unsigned short* ap[5];
#pragma unroll
    for (int s = 0; s < 5; ++s)
        ap[s] = wf + (size_t)(s * 4 + wvid) * 72 * 512 + (size_t)l15 * 32 + quad * 8;

    __syncthreads();   // prm ready

    // prologue: issue corner loads for macro 0 (tap 0, q0 0)
    uint2 wcur; uint4 u00, u01, u10, u11;
    {
        int idx = px * 9 + 0;
        wcur = prw2[idx];
        const unsigned short* xp = xtb + (size_t)pra2[idx] * 256 + (0 + cl) * 32 + sl * 8;
        u00 = ld16(xp); u01 = ld16(xp + 256); u10 = ld16(xp + 16384); u11 = ld16(xp + 16640);
    }

#pragma unroll
    for (int m = 0; m < 18; ++m) {
        const int tap = m >> 1, q0 = (m & 1) * 4;

        float w00 = bf2f((unsigned short)(wcur.x & 0xFFFF));
        float w01 = bf2f((unsigned short)(wcur.x >> 16));
        float w10 = bf2f((unsigned short)(wcur.y & 0xFFFF));
        float w11 = bf2f((unsigned short)(wcur.y >> 16));
        union { uint4 v; unsigned short u[8]; } a00, a01, a10, a11, o;
        a00.v = u00; a01.v = u01; a10.v = u10; a11.v = u11;
#pragma unroll
        for (int j = 0; j < 8; ++j) {
            float v = w00 * bf2f(a00.u[j]) + w01 * bf2f(a01.u[j])
                    + w10 * bf2f(a10.u[j]) + w11 * bf2f(a11.u[j]);
            o.u[j] = f2bf(v);
        }

        if (m < 17) {
            int tapn = (m + 1) >> 1, q0n = ((m + 1) & 1) * 4;
            int idx = px * 9 + tapn;
            wcur = prw2[idx];
            const unsigned short* xp = xtb + (size_t)pra2[idx] * 256 + (q0n + cl) * 32 + sl * 8;
            u00 = ld16(xp); u01 = ld16(xp + 256); u10 = ld16(xp + 16384); u11 = ld16(xp + 16640);
        }

        *(uint4*)&tile[m & 1][cl][px][sl * 8] = o.v;
        asm volatile("s_waitcnt lgkmcnt(0)\n\ts_barrier" ::: "memory");

#pragma unroll
        for (int st = 0; st < 4; ++st) {
            const int kt = tap * 8 + q0 + st;
            short8 bfr = *(const short8*)&tile[m & 1][st][l15][quad * 8];
#pragma unroll
            for (int s = 0; s < 5; ++s) {
                uint4 a = *(const uint4*)(ap[s] + (size_t)kt * 512);
                acc[s] = __builtin_amdgcn_mfma_f32_16x16x32_bf16(*(const short8*)&a, bfr, acc[s], 0, 0, 0);
            }
        }
    }

#pragma unroll
    for (int s = 0; s < 5; ++s) {
        const int cobase = s * 64 + wvid * 16;
        unsigned short* ob; int lco; size_t nper;
        if (cobase < 32)      { ob = qb16; lco = cobase;      nper = (size_t)32 * HW; }
        else if (cobase < 64) { ob = kb16; lco = cobase - 32; nper = (size_t)32 * HW; }
        else                  { ob = vb16; lco = cobase - 64; nper = (size_t)256 * HW; }
        unsigned short* obb = ob + (size_t)b * nper;
#pragma unroll
        for (int r = 0; r < 4; ++r) {
            float val = acc[s][r] + bcat[cobase + (quad << 2) + r];
            obb[(size_t)(lco + (quad << 2) + r) * HW + p0 + l15] = f2bf(val);
        }
    }
}

// ================= Kernel 5: V re-layout [j][cc] -> [cc][j] — R9-proven ==========================
__global__ __launch_bounds__(256) void k_vtrans(
    const unsigned short* __restrict__ vb16, unsigned short* __restrict__ vb16T)
{
    const int jt = blockIdx.x, b = blockIdx.y;
    const int cc = threadIdx.x;
    const unsigned short* src = vb16 + (size_t)b * CHW + (size_t)(jt * 64) * 256 + cc;
    unsigned short* dst = vb16T + (size_t)b * CHW + (size_t)cc * 4096 + jt * 64;
#pragma unroll
    for (int o = 0; o < 8; ++o) {
        union { uint4 v; unsigned short u[8]; } tmp;
#pragma unroll
        for (int j = 0; j < 8; ++j) tmp.u[j] = src[(o * 8 + j) * 256];
        *(uint4*)(dst + o * 8) = tmp.v;
    }
}

// ================= Kernel 6: flash attention — shuffle P-redistribution (R23) ====================
// R12 diagnosis: per-round wall ~2680cy vs ~500cy issue -> bound by intra-round serial chain; the
// largest removable link is the P round-trip (ptl ds_write -> lgkm -> ds_read_b128, ~240cy, also
// the remaining 6.8M bank conflicts). R23 SINGLE CHANGE: build the PV A-frag in-register via
// __shfl. Lane (q,Q') packs w0..w3 = bf16 pairs covering k=4Q'+{0,1},{2,3} and 16+4Q'+{0,1},{2,3}.
// Target lane (q,Q) needs k=8Q..8Q+7 = words of src quads (2Q)&3 and (2Q+1)&3, lo/hi pair selected
// by Q<2. 8 shfl + 4 selects replace write+wait+read; ptl deleted. Rest identical to R19/R18.
#define SM_SHIFT 16.0f
__global__ __launch_bounds__(256) void k_attn(
    const unsigned short* __restrict__ qb16, const unsigned short* __restrict__ kb16,
    const unsigned short* __restrict__ vt, const float* __restrict__ x,
    const float* __restrict__ gamma, float* __restrict__ out)
{
    __shared__ unsigned short Vt[2][2][128][36];  // [round-parity][jh-stream][cc][j]
    __shared__ unsigned short Kt[2][2][32][36];   // [round-parity][ktile][row][j]
    __shared__ float red[2][64][33];

    const int qt = blockIdx.x, ch2 = blockIdx.y, b = blockIdx.z;
    const int t = threadIdx.x;
    const int lane = t & 63;
    const int wv = t >> 6;
    const int g = wv & 1, jh = wv >> 1;
    const int l15 = lane & 15, quad = lane >> 4;
    const int cc0 = ch2 * 128;

    const unsigned short* Qb = qb16 + (size_t)b * (32 * 4096);
    const unsigned short* Kb = kb16 + (size_t)b * (32 * 4096);
    const unsigned short* VT = vt + (size_t)b * CHW;

    const int q0 = qt * 32 + g * 16;
    short8 qfr = *(const short8*)(Qb + (size_t)(q0 + l15) * 32 + quad * 8);

    const int vcc = t >> 2, voff = (t & 3) * 8;   // stages cc = vcc and vcc+64
    const int ktile = t >> 7, ktl = t & 127;
    const int krow = ktl >> 2, koff = (ktl & 3) * 8;

    // shuffle source lanes for P redistribution (constants per thread)
    const int sl0 = l15 + 16 * ((2 * quad) & 3);
    const int sl1 = l15 + 16 * ((2 * quad + 1) & 3);
    const bool hi = quad >= 2;

    float l_i = 0.f;
    float4v acc[2][4];
#pragma unroll
    for (int c2 = 0; c2 < 2; ++c2)
#pragma unroll
        for (int s = 0; s < 4; ++s) acc[c2][s] = (float4v){0.f, 0.f, 0.f, 0.f};

    // tile-load registers (tile r+1 in flight during round r)
    uint4 v00, v01, v10, v11, kv;
#define LOADT(J0)                                                                     \
    {                                                                                 \
        const unsigned short* vp_ = VT + (size_t)(cc0 + vcc) * 4096 + (J0) + voff;    \
        v00 = ld16(vp_);                                                              \
        v01 = ld16(vp_ + 2048);                                                       \
        v10 = ld16(vp_ + (size_t)64 * 4096);                                          \
        v11 = ld16(vp_ + (size_t)64 * 4096 + 2048);                                   \
        kv  = ld16(Kb + (size_t)(ktile * 2048 + (J0) + krow) * 32 + koff);            \
    }
#define WRITET(PB)                                                                    \
    {                                                                                 \
        *(uint4*)&Vt[PB][0][vcc][voff] = v00;                                         \
        *(uint4*)&Vt[PB][1][vcc][voff] = v01;                                         \
        *(uint4*)&Vt[PB][0][64 + vcc][voff] = v10;                                    \
        *(uint4*)&Vt[PB][1][64 + vcc][voff] = v11;                                    \
        *(uint4*)&Kt[PB][ktile][krow][koff] = kv;                                     \
    }

    // prologue: tile 0 -> buf0 (vmcnt waits via register deps), tile 1 into regs
    LOADT(0);
    WRITET(0);
    LOADT(32);

    for (int rnd = 0; rnd < 64; ++rnd) {
        // ONE barrier per round: buf[rnd&1] visible; prior-round readers of buf[(rnd+1)&1] done.
        asm volatile("s_waitcnt lgkmcnt(0)\n\ts_barrier" ::: "memory");
        if (rnd < 63) WRITET((rnd + 1) & 1);       // tile rnd+1 (regs loaded last round)
        if (rnd < 62) LOADT((rnd + 2) * 32);       // tile rnd+2 in flight under compute

        const int pc = rnd & 1;
        short8 kfr0 = *(const short8*)&Kt[pc][jh][l15][quad * 8];
        short8 kfr1 = *(const short8*)&Kt[pc][jh][16 + l15][quad * 8];
        float4v s0 = (float4v){0.f, 0.f, 0.f, 0.f}, s1 = s0;
        s0 = __builtin_amdgcn_mfma_f32_16x16x32_bf16(kfr0, qfr, s0, 0, 0, 0);
        s1 = __builtin_amdgcn_mfma_f32_16x16x32_bf16(kfr1, qfr, s1, 0, 0, 0);
        float p[8]; float ls = 0.f;
#pragma unroll
        for (int r = 0; r < 4; ++r) { p[r] = __expf(s0[r] - SM_SHIFT); ls += p[r]; }
#pragma unroll
        for (int r = 0; r < 4; ++r) { p[4 + r] = __expf(s1[r] - SM_SHIFT); ls += p[4 + r]; }
        l_i += ls;

        // pack: w0,w1 cover k=4*quad+{0,1},{2,3}; w2,w3 cover k=16+4*quad+{0,1},{2,3}
        uint32_t w0 = (uint32_t)f2bf(p[0]) | ((uint32_t)f2bf(p[1]) << 16);
        uint32_t w1 = (uint32_t)f2bf(p[2]) | ((uint32_t)f2bf(p[3]) << 16);
        uint32_t w2 = (uint32_t)f2bf(p[4]) | ((uint32_t)f2bf(p[5]) << 16);
        uint32_t w3 = (uint32_t)f2bf(p[6]) | ((uint32_t)f2bf(p[7]) << 16);

        // redistribute: lane (q,Q) frag k=8Q..8Q+7 from quads (2Q)&3, (2Q+1)&3 (lo words if Q<2)
        int a0 = __shfl((int)w0, sl0), b0 = __shfl((int)w2, sl0);
        int a1 = __shfl((int)w1, sl0), b1 = __shfl((int)w3, sl0);
        int a2 = __shfl((int)w0, sl1), b2 = __shfl((int)w2, sl1);
        int a3 = __shfl((int)w1, sl1), b3 = __shfl((int)w3, sl1);
        union { uint32_t u[4]; short8 s8; } pf;
        pf.u[0] = (uint32_t)(hi ? b0 : a0);
        pf.u[1] = (uint32_t)(hi ? b1 : a1);
        pf.u[2] = (uint32_t)(hi ? b2 : a2);
        pf.u[3] = (uint32_t)(hi ? b3 : a3);
        short8 pfr = pf.s8;

#pragma unroll
        for (int c2 = 0; c2 < 2; ++c2) {
#pragma unroll
            for (int s = 0; s < 4; ++s) {
                short8 vfr = *(const short8*)&Vt[pc][jh][c2 * 64 + s * 16 + l15][quad * 8];
                acc[c2][s] = __builtin_amdgcn_mfma_f32_16x16x32_bf16(pfr, vfr, acc[c2][s], 0, 0, 0);
            }
        }
    }
#undef LOADT
#undef WRITET

    l_i += __shfl_xor(l_i, 16);
    l_i += __shfl_xor(l_i, 32);

    __syncthreads();
    if (jh == 1) {
#pragma unroll
        for (int c2 = 0; c2 < 2; ++c2)
#pragma unroll
            for (int s = 0; s < 4; ++s) *(float4v*)&red[g][lane][c2 * 16 + s * 4] = acc[c2][s];
        red[g][lane][32] = l_i;
    }
    __syncthreads();
    if (jh == 0) {
#pragma unroll
        for (int c2 = 0; c2 < 2; ++c2)
#pragma unroll
            for (int s = 0; s < 4; ++s) {
                float4v o = *(const float4v*)&red[g][lane][c2 * 16 + s * 4];
                acc[c2][s][0] += o[0]; acc[c2][s][1] += o[1];
                acc[c2][s][2] += o[2]; acc[c2][s][3] += o[3];
            }
        l_i += red[g][lane][32];
        float lr[4];
#pragma unroll
        for (int r = 0; r < 4; ++r) lr[r] = __shfl(l_i, (quad << 2) + r);
        const float gm = gamma[0];
        const float* xb = x + (size_t)b * CHW;
        float* ob = out + (size_t)b * CHW;
#pragma unroll
        for (int c2 = 0; c2 < 2; ++c2) {
#pragma unroll
            for (int s = 0; s < 4; ++s) {
#pragma unroll
                for (int r = 0; r < 4; ++r) {
                    int q = q0 + (quad << 2) + r;
                    int cc = cc0 + c2 * 64 + s * 16 + l15;
                    size_t idx = (size_t)q * 256 + cc;
                    ob[idx] = gm * (acc[c2][s][r] / lr[r]) + xb[idx];
                }
            }
        }
    }
}

extern "C" void kernel_launch(void* const* d_in, const int* in_sizes, int n_in,
                              void* d_out, int out_size, void* d_ws, size_t ws_size,
                              hipStream_t stream)
{
    (void)in_sizes; (void)n_in; (void)out_size; (void)ws_size;
    const float* x     = (const float*)d_in[0];
    const float* w_off = (const float*)d_in[1];
    const float* b_off = (const float*)d_in[2];
    const float* wq    = (const float*)d_in[3];
    const float* bq    = (const float*)d_in[4];
    const float* wk    = (const float*)d_in[5];
    const float* bk    = (const float*)d_in[6];
    const float* wv    = (const float*)d_in[7];
    const float* bv    = (const float*)d_in[8];
    const float* gamma = (const float*)d_in[9];
    float* out = (float*)d_out;

    // ws layout (bytes): proven offsets.
    char* ws = (char*)d_ws;
    uint2*          pbw     = (uint2*)(ws + 589824);             //  589824
    uint32_t*       pba     = (uint32_t*)(ws + 1179648);         //  294912
    unsigned short* qb16    = (unsigned short*)(ws + 1474560);   //  524288 [32 c][4096 p] flat
    unsigned short* kb16    = (unsigned short*)(ws + 1998848);   //  524288 [32 c][4096 p] flat
    unsigned short* vb16T   = (unsigned short*)(ws + 2523136);   // 4194304 [cc][4096 j]
    unsigned short* wfb     = (unsigned short*)(ws + 6717440);   // 1474560 frag-order W
    float*          bcat    = (float*)(ws + 8192000);            //    2048
    // d_out scratch (8 MB), time-sliced:
    //   [0, 4.72MB)  off_part  (k_offset_conv -> k_params)
    //   [4MB, 8MB)   xt NHWC bf16 (k_xt; live through k_dgemm)
    //   [0, 4MB)     vb16      (k_dgemm -> k_vtrans)
    //   k_attn overwrites all of d_out last.
    float*          off_part = (float*)d_out;
    unsigned short* vb16     = (unsigned short*)d_out;
    unsigned short* xtb      = (unsigned short*)((char*)d_out + 4194304);

    k_offset_conv<<<dim3(128, 8), 256, 0, stream>>>(x, w_off, off_part);
    k_params<<<dim3(128), 256, 0, stream>>>(off_part, b_off, pbw, pba);
    k_wcat<<<dim3(720), 256, 0, stream>>>(wq, wk, wv, bq, bk, bv, wfb, bcat);
    k_xt<<<dim3(64, 2), 256, 0, stream>>>(x, xtb);
    k_dgemm<<<dim3(512), 256, 0, stream>>>(xtb, pbw, pba, wfb, bcat, qb16, kb16, vb16);
    k_vtrans<<<dim3(64, 2), 256, 0, stream>>>(vb16, vb16T);
    k_attn<<<dim3(128, 2, 2), 256, 0, stream>>>(qb16, kb16, vb16T, x, gamma, out);
}

// Round 15
// 222.859 us; speedup vs baseline: 1.0400x; 1.0400x over previous
//
#include <hip/hip_runtime.h>
#include <math.h>
#include <stdint.h>

#define CIN 256
#define HH 64
#define WW 64
#define HW 4096
#define CHW (CIN * HW) // 1048576

typedef __attribute__((ext_vector_type(8))) short short8;   // 8 bf16 = 4 VGPR (MFMA A/B frag)
typedef __attribute__((ext_vector_type(4))) float float4v;  // MFMA C/D frag

__device__ inline unsigned short f2bf(float f) {
    union { float f; uint32_t u; } v; v.f = f;
    return (unsigned short)((v.u + 0x7FFFu + ((v.u >> 16) & 1u)) >> 16);
}
__device__ inline float bf2f(unsigned short h) {
    union { uint32_t u; float f; } v; v.u = ((uint32_t)h) << 16;
    return v.f;
}
__device__ inline uint4 ld16(const unsigned short* p) {
    uint4 r; __builtin_memcpy(&r, p, 16); return r;
}

// ================= Kernel 1: offset conv, LDS-staged weights (R22-proven) ========================
__global__ __launch_bounds__(256) void k_offset_conv(
    const float* __restrict__ x, const float* __restrict__ w_off,
    float* __restrict__ off_part)
{
    __shared__ float red[4][64][18];
    __shared__ float wlds[32][18][12];   // [ci][co][9 w + 3 pad] = 27.6 KB

    const int bh = blockIdx.x, cg = blockIdx.y;
    const int b = bh >> 6, h = bh & 63;
    const int t = threadIdx.x;
    const int w = t & 63;
    const int wv = __builtin_amdgcn_readfirstlane(t >> 6);

    // cooperative stage: src (co, ci, k) is contiguous per co (c-consecutive 9-blocks)
    for (int i = t; i < 18 * 288; i += 256) {
        int co = i / 288, rem = i - co * 288;   // rem = ci*9 + k
        int ci = rem / 9, k = rem - ci * 9;
        wlds[ci][co][k] = w_off[(size_t)co * (CIN * 9) + (size_t)cg * 288 + rem];
    }
    __syncthreads();

    float acc[18];
#pragma unroll
    for (int i = 0; i < 18; ++i) acc[i] = 0.f;
    const float* xb = x + (size_t)b * CHW;
#pragma unroll 1
    for (int i = 0; i < 8; ++i) {
        const int ci = wv * 8 + i;
        const int c = cg * 32 + ci;
        const float* xc = xb + (size_t)c * HW;
        float r0 = (h > 0)  ? xc[(h - 1) * WW + w] : 0.f;
        float r1 =            xc[h * WW + w];
        float r2 = (h < 63) ? xc[(h + 1) * WW + w] : 0.f;
        float l0 = __shfl_up(r0, 1), l1 = __shfl_up(r1, 1), l2 = __shfl_up(r2, 1);
        float d0 = __shfl_down(r0, 1), d1 = __shfl_down(r1, 1), d2 = __shfl_down(r2, 1);
        if (w == 0)  { l0 = 0.f; l1 = 0.f; l2 = 0.f; }
        if (w == 63) { d0 = 0.f; d1 = 0.f; d2 = 0.f; }
        const float xv[9] = {l0, r0, d0, l1, r1, d1, l2, r2, d2};
#pragma unroll
        for (int co = 0; co < 18; ++co) {
            const float4 wa = *(const float4*)&wlds[ci][co][0];
            const float4 wb = *(const float4*)&wlds[ci][co][4];
            const float w8 = wlds[ci][co][8];
            acc[co] += wa.x * xv[0] + wa.y * xv[1] + wa.z * xv[2] + wa.w * xv[3]
                     + wb.x * xv[4] + wb.y * xv[5] + wb.z * xv[6] + wb.w * xv[7]
                     + w8 * xv[8];
        }
    }
#pragma unroll
    for (int co = 0; co < 18; ++co) red[wv][w][co] = acc[co];
    __syncthreads();
    if (t < 64) {
#pragma unroll
        for (int co = 0; co < 18; ++co) {
            float s = red[0][t][co] + red[1][t][co] + red[2][t][co] + red[3][t][co];
            off_part[((size_t)(cg * 128 + bh)) * 1152 + co * 64 + t] = s;
        }
    }
}

// ================= Kernel 2: patch-form bilinear params (sums 8 conv partials) — R9-proven =======
__global__ __launch_bounds__(256) void k_params(
    const float* __restrict__ off_part, const float* __restrict__ b_off,
    uint2* __restrict__ pbw, uint32_t* __restrict__ pba)
{
    const int bh = blockIdx.x;
    const int h = bh & 63;
    const int t = threadIdx.x;
    for (int r = 0; r < 3; ++r) {
        int sid = t + 256 * r;
        if (sid < 576) {
            int k = sid >> 6, ww = sid & 63;
            float dy = b_off[2 * k], dx = b_off[2 * k + 1];
#pragma unroll
            for (int g = 0; g < 8; ++g) {
                const float* pp = off_part + (size_t)(g * 128 + bh) * 1152;
                dy += pp[(2 * k) * 64 + ww];
                dx += pp[(2 * k + 1) * 64 + ww];
            }
            float py = (float)(h + k / 3 - 1) + dy;
            float px = (float)(ww + k % 3 - 1) + dx;
            float y0f = floorf(py), x0f = floorf(px);
            float fy = py - y0f, fx = px - x0f;
            int y0 = (int)y0f, x0 = (int)x0f;
            int yb = min(max(y0, 0), 62), xb = min(max(x0, 0), 62);
            float wr[2] = {0.f, 0.f}, wc[2] = {0.f, 0.f};
            if (y0 >= 0 && y0 < HH) wr[y0 - yb] += 1.f - fy;
            if (y0 + 1 >= 0 && y0 + 1 < HH) wr[y0 + 1 - yb] += fy;
            if (x0 >= 0 && x0 < WW) wc[x0 - xb] += 1.f - fx;
            if (x0 + 1 >= 0 && x0 + 1 < WW) wc[x0 + 1 - xb] += fx;
            uint2 pw;
            pw.x = (uint32_t)f2bf(wr[0] * wc[0]) | ((uint32_t)f2bf(wr[0] * wc[1]) << 16);
            pw.y = (uint32_t)f2bf(wr[1] * wc[0]) | ((uint32_t)f2bf(wr[1] * wc[1]) << 16);
            pbw[(size_t)bh * 576 + sid] = pw;
            pba[(size_t)bh * 576 + sid] = (uint32_t)(yb * WW + xb);
        }
    }
}

// ================= Kernel 3: W concat + bf16 cast, TAP-MAJOR frag-native layout (R13) ============
__global__ __launch_bounds__(256) void k_wcat(
    const float* __restrict__ wq, const float* __restrict__ wk, const float* __restrict__ wv_,
    const float* __restrict__ bq, const float* __restrict__ bk, const float* __restrict__ bv,
    unsigned short* __restrict__ wf, float* __restrict__ bcat)
{
    int e = (blockIdx.x * 256 + threadIdx.x) * 4;   // flat co*2304+k, 4 consecutive k
    const float* src;
    if (e < 32 * 2304)      src = wq + e;
    else if (e < 64 * 2304) src = wk + (e - 32 * 2304);
    else                    src = wv_ + (e - 64 * 2304);
    float4 v = *(const float4*)src;
    unsigned short o[4] = {f2bf(v.x), f2bf(v.y), f2bf(v.z), f2bf(v.w)};
    int co = e / 2304;
    int k0 = e - co * 2304;
#pragma unroll
    for (int i = 0; i < 4; ++i) {
        int k = k0 + i;
        int c = (k * 7282) >> 16;      // exact /9 for k < 2304
        int tap = k - c * 9;
        int kdp = tap * 256 + c;
        size_t d = ((size_t)(co >> 4) * 72 + (kdp >> 5)) * 512 + (size_t)(co & 15) * 32 + (kdp & 31);
        wf[d] = o[i];
    }
    if (blockIdx.x == 0 && threadIdx.x < 320) {
        int c = threadIdx.x;
        bcat[c] = c < 32 ? bq[c] : (c < 64 ? bk[c - 32] : bv[c - 64]);
    }
}

// ================= Kernel 3b: x NCHW f32 -> NHWC bf16 (channel-dense gather layout) ==============
__global__ __launch_bounds__(256) void k_xt(
    const float* __restrict__ x, unsigned short* __restrict__ xt)
{
    __shared__ float tl[64][65];
    const int b = blockIdx.y, px0 = blockIdx.x * 64;
    const int t = threadIdx.x;
    const float* xb = x + (size_t)b * CHW;
    unsigned short* xo = xt + (size_t)b * CHW;
    for (int cb = 0; cb < 4; ++cb) {
        __syncthreads();
#pragma unroll
        for (int i = 0; i < 16; ++i) {
            int cr = (t >> 6) * 16 + i;
            tl[cr][t & 63] = xb[(size_t)(cb * 64 + cr) * HW + px0 + (t & 63)];
        }
        __syncthreads();
#pragma unroll
        for (int i = 0; i < 2; ++i) {
            int px = t >> 2;
            int sl = (t & 3) + 4 * i;
            union { uint4 v; unsigned short u[8]; } o;
#pragma unroll
            for (int j = 0; j < 8; ++j) o.u[j] = f2bf(tl[sl * 8 + j][px]);
            *(uint4*)(xo + (size_t)(px0 + px) * 256 + cb * 64 + sl * 8) = o.v;
        }
    }
}

// ================= Kernel 4: FUSED sample + GEMM, channel-dense gathers + XCD swizzle (R25) ======
// R25 change: bijective XCD-aware block swizzle (512 blocks % 8 == 0): XCD k processes 64
// CONSECUTIVE 16-px tiles -> pbw/pba rows + xt gather neighborhoods become L2-local (T1).
__global__ __launch_bounds__(256) void k_dgemm(
    const unsigned short* __restrict__ xt, const uint2* __restrict__ pbw,
    const uint32_t* __restrict__ pba, const unsigned short* __restrict__ wf,
    const float* __restrict__ bcat,
    unsigned short* __restrict__ qb16, unsigned short* __restrict__ kb16,
    unsigned short* __restrict__ vb16)
{
    __shared__ uint2 prw2[144];                    // [px*9 + tap]
    __shared__ uint32_t pra2[144];
    __shared__ unsigned short tile[2][4][16][40];  // dbuf x 4 steps x 16px x 32ch(+pad)

    const int bid = blockIdx.x;
    const int blk = ((bid & 7) << 6) | (bid >> 3);   // XCD swizzle: (bid%8)*64 + bid/8
    const int b = blk >> 8;
    const int p0 = (blk & 255) * 16;
    const int bh = b * 64 + (p0 >> 6);
    const int w0 = p0 & 63;

    const int t = threadIdx.x;
    const int lane = t & 63;
    const int l15 = lane & 15, quad = lane >> 4;
    const int wvid = __builtin_amdgcn_readfirstlane(t >> 6);

    if (t < 144) {
        int nl9 = t / 9, tap = t - nl9 * 9;
        int src = bh * 576 + tap * 64 + w0 + nl9;
        prw2[nl9 * 9 + tap] = pbw[src];
        pra2[nl9 * 9 + tap] = pba[src];
    }

    const unsigned short* xtb = xt + (size_t)b * CHW;
    const int px = t >> 4;          // pixel 0..15
    const int cl = (t >> 2) & 3;    // c-block-local (step within macro)
    const int sl = t & 3;           // 8-channel slice within 32

    float4v acc[5];
#pragma unroll
    for (int s = 0; s < 5; ++s) acc[s] = (float4v){0.f, 0.f, 0.f, 0.f};

    const unsigned short* ap[5];
#pragma unroll
    for (int s = 0; s < 5; ++s)
        ap[s] = wf + (size_t)(s * 4 + wvid) * 72 * 512 + (size_t)l15 * 32 + quad * 8;

    __syncthreads();   // prm ready

    // prologue: issue corner loads for macro 0 (tap 0, q0 0)
    uint2 wcur; uint4 u00, u01, u10, u11;
    {
        int idx = px * 9 + 0;
        wcur = prw2[idx];
        const unsigned short* xp = xtb + (size_t)pra2[idx] * 256 + (0 + cl) * 32 + sl * 8;
        u00 = ld16(xp); u01 = ld16(xp + 256); u10 = ld16(xp + 16384); u11 = ld16(xp + 16640);
    }

#pragma unroll
    for (int m = 0; m < 18; ++m) {
        const int tap = m >> 1, q0 = (m & 1) * 4;

        float w00 = bf2f((unsigned short)(wcur.x & 0xFFFF));
        float w01 = bf2f((unsigned short)(wcur.x >> 16));
        float w10 = bf2f((unsigned short)(wcur.y & 0xFFFF));
        float w11 = bf2f((unsigned short)(wcur.y >> 16));
        union { uint4 v; unsigned short u[8]; } a00, a01, a10, a11, o;
        a00.v = u00; a01.v = u01; a10.v = u10; a11.v = u11;
#pragma unroll
        for (int j = 0; j < 8; ++j) {
            float v = w00 * bf2f(a00.u[j]) + w01 * bf2f(a01.u[j])
                    + w10 * bf2f(a10.u[j]) + w11 * bf2f(a11.u[j]);
            o.u[j] = f2bf(v);
        }

        if (m < 17) {
            int tapn = (m + 1) >> 1, q0n = ((m + 1) & 1) * 4;
            int idx = px * 9 + tapn;
            wcur = prw2[idx];
            const unsigned short* xp = xtb + (size_t)pra2[idx] * 256 + (q0n + cl) * 32 + sl * 8;
            u00 = ld16(xp); u01 = ld16(xp + 256); u10 = ld16(xp + 16384); u11 = ld16(xp + 16640);
        }

        *(uint4*)&tile[m & 1][cl][px][sl * 8] = o.v;
        asm volatile("s_waitcnt lgkmcnt(0)\n\ts_barrier" ::: "memory");

#pragma unroll
        for (int st = 0; st < 4; ++st) {
            const int kt = tap * 8 + q0 + st;
            short8 bfr = *(const short8*)&tile[m & 1][st][l15][quad * 8];
#pragma unroll
            for (int s = 0; s < 5; ++s) {
                uint4 a = *(const uint4*)(ap[s] + (size_t)kt * 512);
                acc[s] = __builtin_amdgcn_mfma_f32_16x16x32_bf16(*(const short8*)&a, bfr, acc[s], 0, 0, 0);
            }
        }
    }

#pragma unroll
    for (int s = 0; s < 5; ++s) {
        const int cobase = s * 64 + wvid * 16;
        unsigned short* ob; int lco; size_t nper;
        if (cobase < 32)      { ob = qb16; lco = cobase;      nper = (size_t)32 * HW; }
        else if (cobase < 64) { ob = kb16; lco = cobase - 32; nper = (size_t)32 * HW; }
        else                  { ob = vb16; lco = cobase - 64; nper = (size_t)256 * HW; }
        unsigned short* obb = ob + (size_t)b * nper;
#pragma unroll
        for (int r = 0; r < 4; ++r) {
            float val = acc[s][r] + bcat[cobase + (quad << 2) + r];
            obb[(size_t)(lco + (quad << 2) + r) * HW + p0 + l15] = f2bf(val);
        }
    }
}

// ================= Kernel 5: V re-layout [j][cc] -> [cc][j] — R9-proven ==========================
__global__ __launch_bounds__(256) void k_vtrans(
    const unsigned short* __restrict__ vb16, unsigned short* __restrict__ vb16T)
{
    const int jt = blockIdx.x, b = blockIdx.y;
    const int cc = threadIdx.x;
    const unsigned short* src = vb16 + (size_t)b * CHW + (size_t)(jt * 64) * 256 + cc;
    unsigned short* dst = vb16T + (size_t)b * CHW + (size_t)cc * 4096 + jt * 64;
#pragma unroll
    for (int o = 0; o < 8; ++o) {
        union { uint4 v; unsigned short u[8]; } tmp;
#pragma unroll
        for (int j = 0; j < 8; ++j) tmp.u[j] = src[(o * 8 + j) * 256];
        *(uint4*)(dst + o * 8) = tmp.v;
    }
}

// ================= Kernel 6: flash attention — R12-exact structure + setprio (R25) ===============
// R14 post-mortem: cvt_pk pack FAILED correctness here (absmax 2256) despite passing in R7's
// context — flagged unverified, reverted to the R12-exact manual f2bf pack (measured 71.4us).
// R25 change: s_setprio(1) around the QK and PV MFMA clusters (T5) — waves in a round diverge
// into load-issuing vs MFMA-entering roles; priority lets MFMA waves win issue slots. Hint-only,
// zero correctness risk.
#define SM_SHIFT 16.0f
__global__ __launch_bounds__(256) void k_attn(
    const unsigned short* __restrict__ qb16, const unsigned short* __restrict__ kb16,
    const unsigned short* __restrict__ vt, const float* __restrict__ x,
    const float* __restrict__ gamma, float* __restrict__ out)
{
    __shared__ unsigned short ptl[4][16 * 40];
    __shared__ unsigned short Vt[2][2][128][36];  // [round-parity][jh-stream][cc][j]
    __shared__ unsigned short Kt[2][2][32][36];   // [round-parity][ktile][row][j]
    __shared__ float red[2][64][33];

    const int qt = blockIdx.x, ch2 = blockIdx.y, b = blockIdx.z;
    const int t = threadIdx.x;
    const int lane = t & 63;
    const int wv = t >> 6;
    const int g = wv & 1, jh = wv >> 1;
    const int l15 = lane & 15, quad = lane >> 4;
    const int cc0 = ch2 * 128;

    const unsigned short* Qb = qb16 + (size_t)b * (32 * 4096);
    const unsigned short* Kb = kb16 + (size_t)b * (32 * 4096);
    const unsigned short* VT = vt + (size_t)b * CHW;

    const int q0 = qt * 32 + g * 16;
    short8 qfr = *(const short8*)(Qb + (size_t)(q0 + l15) * 32 + quad * 8);

    const int vcc = t >> 2, voff = (t & 3) * 8;   // stages cc = vcc and vcc+64
    const int ktile = t >> 7, ktl = t & 127;
    const int krow = ktl >> 2, koff = (ktl & 3) * 8;

    float l_i = 0.f;
    float4v acc[2][4];
#pragma unroll
    for (int c2 = 0; c2 < 2; ++c2)
#pragma unroll
        for (int s = 0; s < 4; ++s) acc[c2][s] = (float4v){0.f, 0.f, 0.f, 0.f};
    unsigned short* pw = ptl[wv];

    // tile-load registers (tile r+1 in flight during round r)
    uint4 v00, v01, v10, v11, kv;
#define LOADT(J0)                                                                     \
    {                                                                                 \
        const unsigned short* vp_ = VT + (size_t)(cc0 + vcc) * 4096 + (J0) + voff;    \
        v00 = ld16(vp_);                                                              \
        v01 = ld16(vp_ + 2048);                                                       \
        v10 = ld16(vp_ + (size_t)64 * 4096);                                          \
        v11 = ld16(vp_ + (size_t)64 * 4096 + 2048);                                   \
        kv  = ld16(Kb + (size_t)(ktile * 2048 + (J0) + krow) * 32 + koff);            \
    }
#define WRITET(PB)                                                                    \
    {                                                                                 \
        *(uint4*)&Vt[PB][0][vcc][voff] = v00;                                         \
        *(uint4*)&Vt[PB][1][vcc][voff] = v01;                                         \
        *(uint4*)&Vt[PB][0][64 + vcc][voff] = v10;                                    \
        *(uint4*)&Vt[PB][1][64 + vcc][voff] = v11;                                    \
        *(uint4*)&Kt[PB][ktile][krow][koff] = kv;                                     \
    }

    // prologue: tile 0 -> buf0 (vmcnt waits via register deps), tile 1 into regs
    LOADT(0);
    WRITET(0);
    LOADT(32);

    for (int rnd = 0; rnd < 64; ++rnd) {
        // ONE barrier per round: buf[rnd&1] visible; prior-round readers of buf[(rnd+1)&1] done.
        asm volatile("s_waitcnt lgkmcnt(0)\n\ts_barrier" ::: "memory");
        if (rnd < 63) WRITET((rnd + 1) & 1);       // tile rnd+1 (regs loaded last round)
        if (rnd < 62) LOADT((rnd + 2) * 32);       // tile rnd+2 in flight under compute

        const int pc = rnd & 1;
        short8 kfr0 = *(const short8*)&Kt[pc][jh][l15][quad * 8];
        short8 kfr1 = *(const short8*)&Kt[pc][jh][16 + l15][quad * 8];
        float4v s0 = (float4v){0.f, 0.f, 0.f, 0.f}, s1 = s0;
        __builtin_amdgcn_s_setprio(1);
        s0 = __builtin_amdgcn_mfma_f32_16x16x32_bf16(kfr0, qfr, s0, 0, 0, 0);
        s1 = __builtin_amdgcn_mfma_f32_16x16x32_bf16(kfr1, qfr, s1, 0, 0, 0);
        __builtin_amdgcn_s_setprio(0);
        float p[8]; float ls = 0.f;
#pragma unroll
        for (int r = 0; r < 4; ++r) { p[r] = __expf(s0[r] - SM_SHIFT); ls += p[r]; }
#pragma unroll
        for (int r = 0; r < 4; ++r) { p[4 + r] = __expf(s1[r] - SM_SHIFT); ls += p[4 + r]; }
        l_i += ls;
        union { uint2 v; unsigned short u[4]; } pk0, pk1;
#pragma unroll
        for (int r = 0; r < 4; ++r) { pk0.u[r] = f2bf(p[r]); pk1.u[r] = f2bf(p[4 + r]); }
        *(uint2*)&pw[l15 * 40 + (quad << 2)] = pk0.v;
        *(uint2*)&pw[l15 * 40 + 16 + (quad << 2)] = pk1.v;
        short8 pfr = *(const short8*)&pw[l15 * 40 + quad * 8];
        __builtin_amdgcn_s_setprio(1);
#pragma unroll
        for (int c2 = 0; c2 < 2; ++c2) {
#pragma unroll
            for (int s = 0; s < 4; ++s) {
                short8 vfr = *(const short8*)&Vt[pc][jh][c2 * 64 + s * 16 + l15][quad * 8];
                acc[c2][s] = __builtin_amdgcn_mfma_f32_16x16x32_bf16(pfr, vfr, acc[c2][s], 0, 0, 0);
            }
        }
        __builtin_amdgcn_s_setprio(0);
    }
#undef LOADT
#undef WRITET

    l_i += __shfl_xor(l_i, 16);
    l_i += __shfl_xor(l_i, 32);

    __syncthreads();
    if (jh == 1) {
#pragma unroll
        for (int c2 = 0; c2 < 2; ++c2)
#pragma unroll
            for (int s = 0; s < 4; ++s) *(float4v*)&red[g][lane][c2 * 16 + s * 4] = acc[c2][s];
        red[g][lane][32] = l_i;
    }
    __syncthreads();
    if (jh == 0) {
#pragma unroll
        for (int c2 = 0; c2 < 2; ++c2)
#pragma unroll
            for (int s = 0; s < 4; ++s) {
                float4v o = *(const float4v*)&red[g][lane][c2 * 16 + s * 4];
                acc[c2][s][0] += o[0]; acc[c2][s][1] += o[1];
                acc[c2][s][2] += o[2]; acc[c2][s][3] += o[3];
            }
        l_i += red[g][lane][32];
        float lr[4];
#pragma unroll
        for (int r = 0; r < 4; ++r) lr[r] = __shfl(l_i, (quad << 2) + r);
        const float gm = gamma[0];
        const float* xb = x + (size_t)b * CHW;
        float* ob = out + (size_t)b * CHW;
#pragma unroll
        for (int c2 = 0; c2 < 2; ++c2) {
#pragma unroll
            for (int s = 0; s < 4; ++s) {
#pragma unroll
                for (int r = 0; r < 4; ++r) {
                    int q = q0 + (quad << 2) + r;
                    int cc = cc0 + c2 * 64 + s * 16 + l15;
                    size_t idx = (size_t)q * 256 + cc;
                    ob[idx] = gm * (acc[c2][s][r] / lr[r]) + xb[idx];
                }
            }
        }
    }
}

extern "C" void kernel_launch(void* const* d_in, const int* in_sizes, int n_in,
                              void* d_out, int out_size, void* d_ws, size_t ws_size,
                              hipStream_t stream)
{
    (void)in_sizes; (void)n_in; (void)out_size; (void)ws_size;
    const float* x     = (const float*)d_in[0];
    const float* w_off = (const float*)d_in[1];
    const float* b_off = (const float*)d_in[2];
    const float* wq    = (const float*)d_in[3];
    const float* bq    = (const float*)d_in[4];
    const float* wk    = (const float*)d_in[5];
    const float* bk    = (const float*)d_in[6];
    const float* wv    = (const float*)d_in[7];
    const float* bv    = (const float*)d_in[8];
    const float* gamma = (const float*)d_in[9];
    float* out = (float*)d_out;

    // ws layout (bytes): proven offsets.
    char* ws = (char*)d_ws;
    uint2*          pbw     = (uint2*)(ws + 589824);             //  589824
    uint32_t*       pba     = (uint32_t*)(ws + 1179648);         //  294912
    unsigned short* qb16    = (unsigned short*)(ws + 1474560);   //  524288 [32 c][4096 p] flat
    unsigned short* kb16    = (unsigned short*)(ws + 1998848);   //  524288 [32 c][4096 p] flat
    unsigned short* vb16T   = (unsigned short*)(ws + 2523136);   // 4194304 [cc][4096 j]
    unsigned short* wfb     = (unsigned short*)(ws + 6717440);   // 1474560 frag-order W
    float*          bcat    = (float*)(ws + 8192000);            //    2048
    // d_out scratch (8 MB), time-sliced:
    //   [0, 4.72MB)  off_part  (k_offset_conv -> k_params)
    //   [4MB, 8MB)   xt NHWC bf16 (k_xt; live through k_dgemm)
    //   [0, 4MB)     vb16      (k_dgemm -> k_vtrans)
    //   k_attn overwrites all of d_out last.
    float*          off_part = (float*)d_out;
    unsigned short* vb16     = (unsigned short*)d_out;
    unsigned short* xtb      = (unsigned short*)((char*)d_out + 4194304);

    k_offset_conv<<<dim3(128, 8), 256, 0, stream>>>(x, w_off, off_part);
    k_params<<<dim3(128), 256, 0, stream>>>(off_part, b_off, pbw, pba);
    k_wcat<<<dim3(720), 256, 0, stream>>>(wq, wk, wv, bq, bk, bv, wfb, bcat);
    k_xt<<<dim3(64, 2), 256, 0, stream>>>(x, xtb);
    k_dgemm<<<dim3(512), 256, 0, stream>>>(xtb, pbw, pba, wfb, bcat, qb16, kb16, vb16);
    k_vtrans<<<dim3(64, 2), 256, 0, stream>>>(vb16, vb16T);
    k_attn<<<dim3(128, 2, 2), 256, 0, stream>>>(qb16, kb16, vb16T, x, gamma, out);
}